// Round 3
// baseline (662.365 us; speedup 1.0000x reference)
//
#include <hip/hip_runtime.h>

#define NT 128      // num tags
#define SEQ 1024    // sequence length
#define NB 256      // batch

typedef _Float16 half2v __attribute__((ext_vector_type(2)));

// One DPP max step on the VALU pipe (no DS/lgkmcnt involvement).
#define DPP_MAX_STEP(x, ctrl)                                                   \
    fmaxf((x), __builtin_bit_cast(float, __builtin_amdgcn_update_dpp(           \
        __builtin_bit_cast(int, (x)), __builtin_bit_cast(int, (x)),             \
        (ctrl), 0xf, 0xf, false)))

__device__ __forceinline__ float wave_max_dpp(float x) {
    x = DPP_MAX_STEP(x, 0x111);   // row_shr:1
    x = DPP_MAX_STEP(x, 0x112);   // row_shr:2
    x = DPP_MAX_STEP(x, 0x114);   // row_shr:4
    x = DPP_MAX_STEP(x, 0x118);   // row_shr:8
    x = DPP_MAX_STEP(x, 0x142);   // row_bcast:15
    x = DPP_MAX_STEP(x, 0x143);   // row_bcast:31
    return __builtin_bit_cast(float, __builtin_amdgcn_readlane(
        __builtin_bit_cast(int, x), 63));
}

// Counted-wait barrier: flush ONLY the DS pipe (ds_write of P/wmax must be
// cross-wave visible), then raw s_barrier. Critically, this does NOT drain
// vmcnt -- the emission/mask ring prefetch loads stay in flight across the
// barrier (their s_waitcnt vmcnt(N) lands at the use, 3-4 steps later).
// __syncthreads() would emit s_waitcnt vmcnt(0) before s_barrier and eat a
// full HBM latency every step (the round-2 ~800 cy/step stall).
// sched_barrier(0) fences post-barrier ds_reads from hoisting above it.
__device__ __forceinline__ void barrier_lds_only() {
    asm volatile("s_waitcnt lgkmcnt(0)" ::: "memory");
    __builtin_amdgcn_s_barrier();
    __builtin_amdgcn_sched_barrier(0);
}

// One scan step, 4-wave cooperative version.
// Wave w owns columns [32w,32w+32); lane: col c=32w+(l&31), i-half ih=l>>5.
// P lives in LDS as packed f16 pairs (64 uints), double-buffered (BUF).
// One barrier per step: reads of buffer BUF precede the barrier, the next
// step's writes target BUF (= its BUF^1) only after that barrier, so
// ping-pong needs no second barrier. The 4 per-wave maxes ride the same
// barrier; every thread derives the same global mx/inv/offadd.
#define CRF_STEP(RC, RN, MC, DO_PRE, K, BUF)                                     \
    {                                                                            \
        float mcur = MC;                                                         \
        if (DO_PRE) { RC = emp[(K) * NT]; MC = mpp[K]; }                         \
        const uint4* p4 = (const uint4*)&p_lds[BUF][ih * 32];                    \
        float A0=0.f, A1=0.f, A2=0.f, A3=0.f;                                    \
        _Pragma("unroll")                                                        \
        for (int qi = 0; qi < 8; ++qi) {                                         \
            uint4 q = p4[qi];                                                    \
            A0 = __builtin_amdgcn_fdot2(__builtin_bit_cast(half2v, q.x),         \
                                        E[4*qi+0], A0, false);                   \
            A1 = __builtin_amdgcn_fdot2(__builtin_bit_cast(half2v, q.y),         \
                                        E[4*qi+1], A1, false);                   \
            A2 = __builtin_amdgcn_fdot2(__builtin_bit_cast(half2v, q.z),         \
                                        E[4*qi+2], A2, false);                   \
            A3 = __builtin_amdgcn_fdot2(__builtin_bit_cast(half2v, q.w),         \
                                        E[4*qi+3], A3, false);                   \
        }                                                                        \
        float sv = (A0 + A1) + (A2 + A3);                                        \
        sv += __shfl_xor(sv, 32);        /* combine the two i-halves */          \
        float v = sv * ex;                                                       \
        if (mcur > 0.0f) { cur = v; offset += offadd; }                          \
        float curo = __shfl_xor(cur, 1); /* partner column for f16 pack */       \
        if (ih == 0 && (cl & 1) == 0)                                            \
            p_lds[(BUF)^1][16*w + (cl >> 1)] = __builtin_bit_cast(unsigned int,  \
                __builtin_amdgcn_cvt_pkrtz(cur, curo));                          \
        float wm = wave_max_dpp(cur);                                            \
        if (l == 0) wmax[(BUF)^1][w] = wm;                                       \
        barrier_lds_only();                                                      \
        float4 wv = *(const float4*)&wmax[(BUF)^1][0];                           \
        mx = fmaxf(fmaxf(wv.x, wv.y), fmaxf(wv.z, wv.w));                        \
        inv = __builtin_amdgcn_rcpf(256.0f * mx);                                \
        offadd = __logf(mx) + 5.545177444479562f;                                \
        ex = __expf(RN) * inv;                                                   \
    }

// FOUR WAVES per batch element (one per SIMD of a CU). 256 blocks x 256
// threads. The 128x128 matvec is split 4 ways; P and the per-wave maxes are
// exchanged through double-buffered LDS with one counted-wait barrier per
// step (lgkmcnt-only flush -- ring prefetch loads stay in flight).
__global__ __launch_bounds__(256, 1) void crf_scan_kernel(
    const float* __restrict__ emissions,    // [B,S,T]
    const float* __restrict__ masks,        // [B,S]
    const int*   __restrict__ tags,         // [B,S]
    const float* __restrict__ transitions,  // [T,T] (log domain)
    const float* __restrict__ start_t,      // [T]
    const float* __restrict__ end_t,        // [T]
    float* __restrict__ out_per_batch)      // [B]
{
    const int b   = blockIdx.x;
    const int tid = threadIdx.x;
    const int w   = tid >> 6;     // wave 0..3
    const int l   = tid & 63;     // lane 0..63
    const int cl  = l & 31;       // column within wave
    const int ih  = l >> 5;       // which half of the i (row) range
    const int c   = 32 * w + cl;  // owned output column
    const int i0  = 64 * ih;      // start of this lane's i range

    __shared__ __align__(16) unsigned int p_lds[2][64]; // packed f16 P pairs
    __shared__ __align__(16) float        wmax[2][4];   // per-wave maxes
    __shared__ float redA[4], redB[4], redC[4];         // epilogue reductions
    __shared__ float msk_s[SEQ];

    // ---- E fragment: rows i0+2r, i0+2r+1 of column c, prob domain f16 ----
    half2v E[32];
    #pragma unroll
    for (int r = 0; r < 32; ++r) {
        float ea = transitions[(i0 + 2*r    ) * NT + c];
        float ob = transitions[(i0 + 2*r + 1) * NT + c];
        E[r] = half2v{(_Float16)__expf(ea), (_Float16)__expf(ob)};
    }

    for (int s = tid; s < SEQ; s += 256)
        msk_s[s] = masks[b * SEQ + s];

    // ---- init: P = exp(start), offset = 0 ----
    float cur = __expf(start_t[c]);
    float offset = 0.0f;

    {
        float curo = __shfl_xor(cur, 1);
        if (ih == 0 && (cl & 1) == 0)
            p_lds[0][16*w + (cl >> 1)] = __builtin_bit_cast(unsigned int,
                __builtin_amdgcn_cvt_pkrtz(cur, curo));
        float wm = wave_max_dpp(cur);
        if (l == 0) wmax[0][w] = wm;
    }
    __syncthreads();

    float4 wv0 = *(const float4*)&wmax[0][0];
    float mx   = fmaxf(fmaxf(wv0.x, wv0.y), fmaxf(wv0.z, wv0.w));
    float inv  = __builtin_amdgcn_rcpf(256.0f * mx);
    float offadd = __logf(mx) + 5.545177444479562f;   // log(256*mx)

    const float* eb  = emissions + (size_t)b * SEQ * NT;
    const float* mkp = masks + b * SEQ;

    // depth-4 rings: slot k holds em/mask for step s with s&3==k (scalar)
    float ring0 = eb[(size_t)0 * NT + c];
    float ring1 = eb[(size_t)1 * NT + c];
    float ring2 = eb[(size_t)2 * NT + c];
    float ring3 = eb[(size_t)3 * NT + c];
    float mr0 = mkp[0], mr1 = mkp[1], mr2 = mkp[2], mr3 = mkp[3];

    float ex = __expf(ring0) * inv;

    const float* emp = eb + 4 * NT + c;   // em[s+4] for s=0
    const float* mpp = mkp + 4;

    // main loop: steps 0..1019, unrolled x4 (ring slots static; BUF = s&1)
    for (int it = 0; it < (SEQ - 4) / 4; ++it) {
        CRF_STEP(ring0, ring1, mr0, true, 0, 0)
        CRF_STEP(ring1, ring2, mr1, true, 1, 1)
        CRF_STEP(ring2, ring3, mr2, true, 2, 0)
        CRF_STEP(ring3, ring0, mr3, true, 3, 1)
        emp += 4 * NT;
        mpp += 4;
    }
    // tail: steps 1020..1023 (no prefetch)
    CRF_STEP(ring0, ring1, mr0, false, 0, 0)
    CRF_STEP(ring1, ring2, mr1, false, 0, 1)
    CRF_STEP(ring2, ring3, mr2, false, 0, 0)
    CRF_STEP(ring3, ring3, mr3, false, 0, 1)

    // ---- log_z = offset + log( sum_j P_j * exp(end_j) ) ----
    float term = (ih == 0) ? cur * __expf(end_t[c]) : 0.0f;
    #pragma unroll
    for (int off = 32; off; off >>= 1)
        term += __shfl_xor(term, off);
    if (l == 0) redA[w] = term;

    // ---- gold-path score (256 threads, 4 s-iters each) ----
    const int tbase = b * SEQ;
    float sc = 0.0f, sm = 0.0f;
    for (int s = tid; s < SEQ; s += 256) {
        float m = msk_s[s];
        sm += m;
        if (s < SEQ - 1) {
            int tg  = tags[tbase + s];
            int tg1 = tags[tbase + s + 1];
            sc += eb[(size_t)s * NT + tg] * m;
            sc += transitions[tg * NT + tg1] * msk_s[s + 1];
        }
    }
    #pragma unroll
    for (int off = 32; off; off >>= 1) {
        sc += __shfl_xor(sc, off);
        sm += __shfl_xor(sm, off);
    }
    if (l == 0) { redB[w] = sc; redC[w] = sm; }
    __syncthreads();

    if (tid == 0) {
        float term_t = (redA[0] + redA[1]) + (redA[2] + redA[3]);
        float log_z  = offset + __logf(term_t);
        float sct    = (redB[0] + redB[1]) + (redB[2] + redB[3]);
        float smt    = (redC[0] + redC[1]) + (redC[2] + redC[3]);
        int tg0 = tags[tbase];
        int tgl = tags[tbase + SEQ - 1];
        sct += start_t[tg0];
        int last_ix = (int)fmaxf(smt - 1.0f, 0.0f);
        float ml = msk_s[SEQ - 1];
        sct += eb[(size_t)last_ix * NT + tgl] * ml;
        sct += end_t[tgl] * ml;
        out_per_batch[b] = log_z - sct;
    }
}

// mean over batch -> scalar output
__global__ void crf_reduce_kernel(const float* __restrict__ pb, float* __restrict__ out)
{
    float v = pb[threadIdx.x];   // 256 threads, one per batch
    #pragma unroll
    for (int off = 32; off; off >>= 1)
        v += __shfl_xor(v, off);
    __shared__ float s4[4];
    if ((threadIdx.x & 63) == 0) s4[threadIdx.x >> 6] = v;
    __syncthreads();
    if (threadIdx.x == 0)
        out[0] = (s4[0] + s4[1] + s4[2] + s4[3]) * (1.0f / 256.0f);
}

extern "C" void kernel_launch(void* const* d_in, const int* in_sizes, int n_in,
                              void* d_out, int out_size, void* d_ws, size_t ws_size,
                              hipStream_t stream) {
    const float* emissions   = (const float*)d_in[0];
    const float* masks       = (const float*)d_in[1];
    const int*   tags        = (const int*)  d_in[2];
    const float* transitions = (const float*)d_in[3];
    const float* start_t     = (const float*)d_in[4];
    const float* end_t       = (const float*)d_in[5];
    float* per_batch = (float*)d_ws;

    crf_scan_kernel<<<NB, 256, 0, stream>>>(emissions, masks, tags, transitions,
                                            start_t, end_t, per_batch);
    crf_reduce_kernel<<<1, 256, 0, stream>>>(per_batch, (float*)d_out);
}

// Round 4
// 562.672 us; speedup vs baseline: 1.1772x; 1.1772x over previous
//
#include <hip/hip_runtime.h>

#define NT 128      // num tags
#define SEQ 1024    // sequence length
#define NB 256      // batch

typedef _Float16 half2v __attribute__((ext_vector_type(2)));

// One DPP max step on the VALU pipe (no DS/lgkmcnt involvement).
#define DPP_MAX_STEP(x, ctrl)                                                   \
    fmaxf((x), __builtin_bit_cast(float, __builtin_amdgcn_update_dpp(           \
        __builtin_bit_cast(int, (x)), __builtin_bit_cast(int, (x)),             \
        (ctrl), 0xf, 0xf, false)))

__device__ __forceinline__ float wave_max_dpp(float x) {
    x = DPP_MAX_STEP(x, 0x111);   // row_shr:1
    x = DPP_MAX_STEP(x, 0x112);   // row_shr:2
    x = DPP_MAX_STEP(x, 0x114);   // row_shr:4
    x = DPP_MAX_STEP(x, 0x118);   // row_shr:8
    x = DPP_MAX_STEP(x, 0x142);   // row_bcast:15
    x = DPP_MAX_STEP(x, 0x143);   // row_bcast:31
    return __builtin_bit_cast(float, __builtin_amdgcn_readlane(
        __builtin_bit_cast(int, x), 63));
}

// lane[i] + lane[i^32], all on the VALU pipe via v_permlane32_swap_b32
// (gfx950). With a=b=x, after the swap a+b == x[i&31] + x[(i&31)+32] in
// every lane under either swap-semantics convention -- identical value and
// identical add order to sv + __shfl_xor(sv,32), but no ds_bpermute round
// trip (~150-250 cy) on the serial chain.
__device__ __forceinline__ float cross32_add(float x) {
    float a = x, b = x;
    asm volatile("v_permlane32_swap_b32 %0, %1" : "+v"(a), "+v"(b));
    return a + b;
}

// lane[i^1] via DPP quad_perm [1,0,3,2] (ctrl 0xB1) -- VALU, exact, replaces
// __shfl_xor(cur,1)'s ds_bpermute.
__device__ __forceinline__ float swap1_dpp(float x) {
    return __builtin_bit_cast(float, __builtin_amdgcn_update_dpp(
        0, __builtin_bit_cast(int, x), 0xB1, 0xf, 0xf, true));
}

// One scan step, 4-wave cooperative version.
// Wave w owns columns [32w,32w+32); lane: col c=32w+(l&31), i-half ih=l>>5.
// P lives in LDS as packed f16 pairs (64 uints), double-buffered (BUF).
// One __syncthreads per step: reads of buffer BUF precede the barrier, the
// next step's writes target BUF^1 only after it (ping-pong, no 2nd barrier).
// The only DS traffic on the critical chain is the unavoidable cross-wave P
// exchange (ds_write + post-barrier ds_read); both shfl exchanges are VALU.
#define CRF_STEP(RC, RN, MC, DO_PRE, K, BUF)                                     \
    {                                                                            \
        float mcur = MC;                                                         \
        if (DO_PRE) { RC = emp[(K) * NT]; MC = mpp[K]; }                         \
        float eRN = __expf(RN);          /* hoisted off the post-barrier path */ \
        const uint4* p4 = (const uint4*)&p_lds[BUF][ih * 32];                    \
        float A0=0.f, A1=0.f, A2=0.f, A3=0.f;                                    \
        _Pragma("unroll")                                                        \
        for (int qi = 0; qi < 8; ++qi) {                                         \
            uint4 q = p4[qi];                                                    \
            A0 = __builtin_amdgcn_fdot2(__builtin_bit_cast(half2v, q.x),         \
                                        E[4*qi+0], A0, false);                   \
            A1 = __builtin_amdgcn_fdot2(__builtin_bit_cast(half2v, q.y),         \
                                        E[4*qi+1], A1, false);                   \
            A2 = __builtin_amdgcn_fdot2(__builtin_bit_cast(half2v, q.z),         \
                                        E[4*qi+2], A2, false);                   \
            A3 = __builtin_amdgcn_fdot2(__builtin_bit_cast(half2v, q.w),         \
                                        E[4*qi+3], A3, false);                   \
        }                                                                        \
        float sv = cross32_add((A0 + A1) + (A2 + A3));                           \
        float v = sv * ex;                                                       \
        if (mcur > 0.0f) { cur = v; offset += offadd; }                          \
        float curo = swap1_dpp(cur);     /* partner column for f16 pack */       \
        if (ih == 0 && (cl & 1) == 0)                                            \
            p_lds[(BUF)^1][16*w + (cl >> 1)] = __builtin_bit_cast(unsigned int,  \
                __builtin_amdgcn_cvt_pkrtz(cur, curo));                          \
        float wm = wave_max_dpp(cur);                                            \
        if (l == 0) wmax[(BUF)^1][w] = wm;                                       \
        __syncthreads();                                                         \
        float4 wv = *(const float4*)&wmax[(BUF)^1][0];                           \
        mx = fmaxf(fmaxf(wv.x, wv.y), fmaxf(wv.z, wv.w));                        \
        inv = __builtin_amdgcn_rcpf(256.0f * mx);                                \
        offadd = __logf(mx) + 5.545177444479562f;                                \
        ex = eRN * inv;                                                          \
    }

// FOUR WAVES per batch element (one per SIMD of a CU). 256 blocks x 256
// threads. The 128x128 matvec is split 4 ways; P and the per-wave maxes are
// exchanged through double-buffered LDS. All other cross-lane traffic
// (i-half combine, pack-partner exchange, wave max) runs on the VALU
// (permlane32_swap / DPP), keeping the DS pipe to one round trip per step.
__global__ __launch_bounds__(256, 1) void crf_scan_kernel(
    const float* __restrict__ emissions,    // [B,S,T]
    const float* __restrict__ masks,        // [B,S]
    const int*   __restrict__ tags,         // [B,S]
    const float* __restrict__ transitions,  // [T,T] (log domain)
    const float* __restrict__ start_t,      // [T]
    const float* __restrict__ end_t,        // [T]
    float* __restrict__ out_per_batch)      // [B]
{
    const int b   = blockIdx.x;
    const int tid = threadIdx.x;
    const int w   = tid >> 6;     // wave 0..3
    const int l   = tid & 63;     // lane 0..63
    const int cl  = l & 31;       // column within wave
    const int ih  = l >> 5;       // which half of the i (row) range
    const int c   = 32 * w + cl;  // owned output column
    const int i0  = 64 * ih;      // start of this lane's i range

    __shared__ __align__(16) unsigned int p_lds[2][64]; // packed f16 P pairs
    __shared__ __align__(16) float        wmax[2][4];   // per-wave maxes
    __shared__ float redA[4], redB[4], redC[4];         // epilogue reductions
    __shared__ float msk_s[SEQ];

    // ---- E fragment: rows i0+2r, i0+2r+1 of column c, prob domain f16 ----
    half2v E[32];
    #pragma unroll
    for (int r = 0; r < 32; ++r) {
        float ea = transitions[(i0 + 2*r    ) * NT + c];
        float ob = transitions[(i0 + 2*r + 1) * NT + c];
        E[r] = half2v{(_Float16)__expf(ea), (_Float16)__expf(ob)};
    }

    for (int s = tid; s < SEQ; s += 256)
        msk_s[s] = masks[b * SEQ + s];

    // ---- init: P = exp(start), offset = 0 ----
    float cur = __expf(start_t[c]);
    float offset = 0.0f;

    {
        float curo = swap1_dpp(cur);
        if (ih == 0 && (cl & 1) == 0)
            p_lds[0][16*w + (cl >> 1)] = __builtin_bit_cast(unsigned int,
                __builtin_amdgcn_cvt_pkrtz(cur, curo));
        float wm = wave_max_dpp(cur);
        if (l == 0) wmax[0][w] = wm;
    }
    __syncthreads();

    float4 wv0 = *(const float4*)&wmax[0][0];
    float mx   = fmaxf(fmaxf(wv0.x, wv0.y), fmaxf(wv0.z, wv0.w));
    float inv  = __builtin_amdgcn_rcpf(256.0f * mx);
    float offadd = __logf(mx) + 5.545177444479562f;   // log(256*mx)

    const float* eb  = emissions + (size_t)b * SEQ * NT;
    const float* mkp = masks + b * SEQ;

    // depth-4 rings: slot k holds em/mask for step s with s&3==k (scalar)
    float ring0 = eb[(size_t)0 * NT + c];
    float ring1 = eb[(size_t)1 * NT + c];
    float ring2 = eb[(size_t)2 * NT + c];
    float ring3 = eb[(size_t)3 * NT + c];
    float mr0 = mkp[0], mr1 = mkp[1], mr2 = mkp[2], mr3 = mkp[3];

    float ex = __expf(ring0) * inv;

    const float* emp = eb + 4 * NT + c;   // em[s+4] for s=0
    const float* mpp = mkp + 4;

    // main loop: steps 0..1019, unrolled x4 (ring slots static; BUF = s&1)
    for (int it = 0; it < (SEQ - 4) / 4; ++it) {
        CRF_STEP(ring0, ring1, mr0, true, 0, 0)
        CRF_STEP(ring1, ring2, mr1, true, 1, 1)
        CRF_STEP(ring2, ring3, mr2, true, 2, 0)
        CRF_STEP(ring3, ring0, mr3, true, 3, 1)
        emp += 4 * NT;
        mpp += 4;
    }
    // tail: steps 1020..1023 (no prefetch)
    CRF_STEP(ring0, ring1, mr0, false, 0, 0)
    CRF_STEP(ring1, ring2, mr1, false, 0, 1)
    CRF_STEP(ring2, ring3, mr2, false, 0, 0)
    CRF_STEP(ring3, ring3, mr3, false, 0, 1)

    // ---- log_z = offset + log( sum_j P_j * exp(end_j) ) ----
    float term = (ih == 0) ? cur * __expf(end_t[c]) : 0.0f;
    #pragma unroll
    for (int off = 32; off; off >>= 1)
        term += __shfl_xor(term, off);
    if (l == 0) redA[w] = term;

    // ---- gold-path score (256 threads, 4 s-iters each) ----
    const int tbase = b * SEQ;
    float sc = 0.0f, sm = 0.0f;
    for (int s = tid; s < SEQ; s += 256) {
        float m = msk_s[s];
        sm += m;
        if (s < SEQ - 1) {
            int tg  = tags[tbase + s];
            int tg1 = tags[tbase + s + 1];
            sc += eb[(size_t)s * NT + tg] * m;
            sc += transitions[tg * NT + tg1] * msk_s[s + 1];
        }
    }
    #pragma unroll
    for (int off = 32; off; off >>= 1) {
        sc += __shfl_xor(sc, off);
        sm += __shfl_xor(sm, off);
    }
    if (l == 0) { redB[w] = sc; redC[w] = sm; }
    __syncthreads();

    if (tid == 0) {
        float term_t = (redA[0] + redA[1]) + (redA[2] + redA[3]);
        float log_z  = offset + __logf(term_t);
        float sct    = (redB[0] + redB[1]) + (redB[2] + redB[3]);
        float smt    = (redC[0] + redC[1]) + (redC[2] + redC[3]);
        int tg0 = tags[tbase];
        int tgl = tags[tbase + SEQ - 1];
        sct += start_t[tg0];
        int last_ix = (int)fmaxf(smt - 1.0f, 0.0f);
        float ml = msk_s[SEQ - 1];
        sct += eb[(size_t)last_ix * NT + tgl] * ml;
        sct += end_t[tgl] * ml;
        out_per_batch[b] = log_z - sct;
    }
}

// mean over batch -> scalar output
__global__ void crf_reduce_kernel(const float* __restrict__ pb, float* __restrict__ out)
{
    float v = pb[threadIdx.x];   // 256 threads, one per batch
    #pragma unroll
    for (int off = 32; off; off >>= 1)
        v += __shfl_xor(v, off);
    __shared__ float s4[4];
    if ((threadIdx.x & 63) == 0) s4[threadIdx.x >> 6] = v;
    __syncthreads();
    if (threadIdx.x == 0)
        out[0] = (s4[0] + s4[1] + s4[2] + s4[3]) * (1.0f / 256.0f);
}

extern "C" void kernel_launch(void* const* d_in, const int* in_sizes, int n_in,
                              void* d_out, int out_size, void* d_ws, size_t ws_size,
                              hipStream_t stream) {
    const float* emissions   = (const float*)d_in[0];
    const float* masks       = (const float*)d_in[1];
    const int*   tags        = (const int*)  d_in[2];
    const float* transitions = (const float*)d_in[3];
    const float* start_t     = (const float*)d_in[4];
    const float* end_t       = (const float*)d_in[5];
    float* per_batch = (float*)d_ws;

    crf_scan_kernel<<<NB, 256, 0, stream>>>(emissions, masks, tags, transitions,
                                            start_t, end_t, per_batch);
    crf_reduce_kernel<<<1, 256, 0, stream>>>(per_batch, (float*)d_out);
}